// Round 1
// baseline (1345.413 us; speedup 1.0000x reference)
//
#include <hip/hip_runtime.h>

#define DEV __device__ __forceinline__

typedef __attribute__((ext_vector_type(8))) short short8;
typedef __attribute__((ext_vector_type(8))) __bf16 bf8_t;
typedef __attribute__((ext_vector_type(4))) float f32x4;
typedef __attribute__((ext_vector_type(4))) unsigned int u32x4;
typedef __attribute__((ext_vector_type(4))) unsigned short u16x4;

DEV unsigned short f2bf(float f){
  union { float f; unsigned u; } x; x.f = f;
  unsigned r = x.u + 0x7fffu + ((x.u >> 16) & 1u);
  return (unsigned short)(r >> 16);
}
DEV unsigned pk2(float a, float b){
  return (unsigned)f2bf(a) | ((unsigned)f2bf(b) << 16);
}
DEV void g2l16(const void* g, const void* l){
  __builtin_amdgcn_global_load_lds((const __attribute__((address_space(1))) void*)g,
                                   (__attribute__((address_space(3))) void*)l, 16, 0, 0);
}
DEV f32x4 mfma16(short8 a, short8 b, f32x4 c){
  return __builtin_amdgcn_mfma_f32_16x16x32_bf16(
      __builtin_bit_cast(bf8_t, a), __builtin_bit_cast(bf8_t, b), c, 0, 0, 0);
}

// ---------------- fp32 -> bf16 convert ----------------
__global__ __launch_bounds__(256) void k_cvt(const float* __restrict__ src,
                                             unsigned short* __restrict__ dst, int n4){
  int stride = gridDim.x * 256;
  for (int i = blockIdx.x * 256 + threadIdx.x; i < n4; i += stride){
    float4 v = ((const float4*)src)[i];
    u16x4 o; o.x = f2bf(v.x); o.y = f2bf(v.y); o.z = f2bf(v.z); o.w = f2bf(v.w);
    ((u16x4*)dst)[i] = o;
  }
}

// ---------------- QKV GEMM: C = x @ W^T + b, fused RoPE, writes Q(bf16 ws) / K,V(fp32 cache) ----
// 128x128 tile, BK=64, 4 waves each computing a 64x64 quadrant of 16x16x32 MFMAs.
template<int USE_WB>
__global__ __launch_bounds__(256, 2) void k_gemm(
    const unsigned short* __restrict__ xb,
    const unsigned short* __restrict__ wb,
    const float* __restrict__ wq, const float* __restrict__ wk, const float* __restrict__ wv,
    const float* __restrict__ bq, const float* __restrict__ bk, const float* __restrict__ bv,
    const float* __restrict__ fcos, const float* __restrict__ fsin,
    const int* __restrict__ spp,
    unsigned short* __restrict__ Qb,
    float* __restrict__ ck, float* __restrict__ cv)
{
  __shared__ __align__(16) short As[128*64];
  __shared__ __align__(16) short Bs[128*64];
  const int tid  = threadIdx.x;
  const int lane = tid & 63, w = tid >> 6;
  const int l15  = lane & 15, quad = lane >> 4;
  const int z  = blockIdx.z;
  const int tn = blockIdx.x >> 4, tm = blockIdx.x & 15;
  const int m0 = tm * 128, n0 = tn * 128;
  const int sp = *spp;
  const float* Wz = (z == 0) ? wq : (z == 1) ? wk : wv;
  const float* Bz = (z == 0) ? bq : (z == 1) ? bk : bv;
  const unsigned short* wbz = wb + (size_t)z * 4096 * 4096;
  const int wm = w >> 1, wn = w & 1;

  f32x4 acc[4][4];
  #pragma unroll
  for (int i = 0; i < 4; i++)
    #pragma unroll
    for (int j = 0; j < 4; j++) acc[i][j] = (f32x4)0.f;

  for (int kt = 0; kt < 64; ++kt){
    const int k0 = kt * 64;
    // stage A (bf16) via global_load_lds, chunk-swizzled: LDS[row][c'] = G[row][c'^(row&7)]
    #pragma unroll
    for (int i = 0; i < 4; i++){
      int ci = (w*4 + i)*64 + lane;
      int row = ci >> 3, cc = (ci & 7) ^ (row & 7);
      g2l16(xb + (size_t)(m0 + row)*4096 + k0 + cc*8, (char*)As + (w*4 + i)*1024);
    }
    if (USE_WB){
      #pragma unroll
      for (int i = 0; i < 4; i++){
        int ci = (w*4 + i)*64 + lane;
        int row = ci >> 3, cc = (ci & 7) ^ (row & 7);
        g2l16(wbz + (size_t)(n0 + row)*4096 + k0 + cc*8, (char*)Bs + (w*4 + i)*1024);
      }
    } else {
      #pragma unroll
      for (int j = 0; j < 4; j++){
        int ci = j*256 + tid;
        int row = ci >> 3, cc = (ci & 7) ^ (row & 7);
        const float4* gp = (const float4*)(Wz + (size_t)(n0 + row)*4096 + k0 + cc*8);
        float4 f0 = gp[0], f1 = gp[1];
        u32x4 p; p.x = pk2(f0.x, f0.y); p.y = pk2(f0.z, f0.w);
                 p.z = pk2(f1.x, f1.y); p.w = pk2(f1.z, f1.w);
        *(u32x4*)&Bs[ci*8] = p;
      }
    }
    __syncthreads();
    #pragma unroll
    for (int ks = 0; ks < 2; ++ks){
      short8 af[4], bf[4];
      #pragma unroll
      for (int mi = 0; mi < 4; mi++){
        int row = wm*64 + mi*16 + l15;
        int cc = (ks*4 + quad) ^ (row & 7);
        af[mi] = *(const short8*)&As[row*64 + cc*8];
      }
      #pragma unroll
      for (int ni = 0; ni < 4; ni++){
        int row = wn*64 + ni*16 + l15;
        int cc = (ks*4 + quad) ^ (row & 7);
        bf[ni] = *(const short8*)&Bs[row*64 + cc*8];
      }
      #pragma unroll
      for (int mi = 0; mi < 4; mi++)
        #pragma unroll
        for (int ni = 0; ni < 4; ni++)
          acc[mi][ni] = mfma16(af[mi], bf[ni], acc[mi][ni]);
    }
    __syncthreads();
  }

  // epilogue: bias, RoPE (Q,K), 1/sqrt(128) folded into Q, scatter stores
  #pragma unroll
  for (int ni = 0; ni < 4; ni++){
    const int col = n0 + wn*64 + ni*16 + l15;
    const float bias_v = Bz[col];
    #pragma unroll
    for (int mi = 0; mi < 4; mi++){
      #pragma unroll
      for (int r = 0; r < 4; r++){
        int rowl = wm*64 + mi*16 + quad*4 + r;
        int m = m0 + rowl;
        int s = m & 511, bb = m >> 9;
        float v = acc[mi][ni][r] + bias_v;
        if (z < 2){
          int fi = (col & 127) >> 1;
          float c = fcos[s*64 + fi], sn = fsin[s*64 + fi];
          float vo = __shfl_xor(v, 1);
          v = (lane & 1) ? (vo*sn + v*c) : (v*c - vo*sn);
        }
        if (z == 0){
          Qb[(size_t)m*4096 + col] = f2bf(v * 0.08838834764831843f);
        } else {
          float* dst = (z == 1) ? ck : cv;
          dst[(((size_t)bb*4096 + sp + s)*32 + (col >> 7))*128 + (col & 127)] = v;
        }
      }
    }
  }
}

// ---------------- Flash attention over full KV cache ----------------
// grid: 512 blocks = (b*32+h)*4 + qtile. 4 waves, each owns a 32-row Q band.
__global__ __launch_bounds__(256, 2) void k_attn(
    const unsigned short* __restrict__ Qb,
    const float* __restrict__ ck, const float* __restrict__ cv,
    const int* __restrict__ spp,
    float* __restrict__ out)
{
  __shared__ __align__(16) short QsP[128*128];  // Q staging [row][128]; reused as P [row][64]
  __shared__ __align__(16) short Ks [64*128];   // [key][128d], chunk-swizzled ^(key&15)
  __shared__ __align__(16) short Vts[128*64];   // [d][64key],  chunk-swizzled ^(d&7)

  const int tid  = threadIdx.x;
  const int lane = tid & 63, w = tid >> 6;
  const int l15  = lane & 15, quad = lane >> 4;
  const int bh = blockIdx.x >> 2, qt = blockIdx.x & 3;
  const int b = bh >> 5, h = bh & 31;
  const int sp = *spp;
  const int nkt = (sp + 512) >> 6;
  const float LOG2E = 1.4426950408889634f;

  // stage Q tile (128 rows x 128 d bf16)
  {
    const size_t qbase = (size_t)(b*512 + qt*128)*4096 + h*128;
    #pragma unroll
    for (int i = 0; i < 8; i++){
      int ci = (w*8 + i)*64 + lane;
      int row = ci >> 4, cc = (ci & 15) ^ (row & 15);
      g2l16(Qb + qbase + (size_t)row*4096 + cc*8, (char*)QsP + (w*8 + i)*1024);
    }
  }
  __syncthreads();
  short8 qf[2][4];
  #pragma unroll
  for (int mi = 0; mi < 2; mi++)
    #pragma unroll
    for (int ks = 0; ks < 4; ks++){
      int row = w*32 + mi*16 + l15;
      int cc = (ks*4 + quad) ^ (row & 15);
      qf[mi][ks] = *(const short8*)&QsP[row*128 + cc*8];
    }
  __syncthreads();  // QsP region reused as P from here on

  f32x4 oacc[2][8];
  #pragma unroll
  for (int mi = 0; mi < 2; mi++)
    #pragma unroll
    for (int ni = 0; ni < 8; ni++) oacc[mi][ni] = (f32x4)0.f;
  float Mx[2][4], Ln[2][4];
  #pragma unroll
  for (int mi = 0; mi < 2; mi++)
    #pragma unroll
    for (int r = 0; r < 4; r++){ Mx[mi][r] = -1e30f; Ln[mi][r] = 0.f; }

  for (int kb = 0; kb < nkt; ++kb){
    // stage K tile (64 keys x 128 d), fp32 -> bf16
    #pragma unroll
    for (int j = 0; j < 4; j++){
      int ci = j*256 + tid;
      int key = ci >> 4, cc = (ci & 15) ^ (key & 15);
      const float* gp = ck + (((size_t)b*4096 + kb*64 + key)*32 + h)*128 + cc*8;
      float4 f0 = ((const float4*)gp)[0], f1 = ((const float4*)gp)[1];
      u32x4 p; p.x = pk2(f0.x, f0.y); p.y = pk2(f0.z, f0.w);
               p.z = pk2(f1.x, f1.y); p.w = pk2(f1.z, f1.w);
      *(u32x4*)&Ks[ci*8] = p;
    }
    // stage V^T tile (128 d x 64 keys): per-lane key-strided loads, coalesced across lanes in d
    {
      int d = tid & 127, kg = tid >> 7;
      #pragma unroll
      for (int cc4 = 0; cc4 < 4; ++cc4){
        int c = kg*4 + cc4;
        int cp = c ^ (d & 7);
        size_t vbase = (((size_t)b*4096 + kb*64 + c*8)*32 + h)*128 + d;
        float f[8];
        #pragma unroll
        for (int j = 0; j < 8; j++) f[j] = cv[vbase + (size_t)j*4096];
        u32x4 p; p.x = pk2(f[0], f[1]); p.y = pk2(f[2], f[3]);
                 p.z = pk2(f[4], f[5]); p.w = pk2(f[6], f[7]);
        *(u32x4*)&Vts[d*64 + cp*8] = p;
      }
    }
    __syncthreads();

    // S = Q K^T (scores pre-scaled via Q)
    f32x4 sa[2][4];
    #pragma unroll
    for (int mi = 0; mi < 2; mi++)
      #pragma unroll
      for (int ni = 0; ni < 4; ni++) sa[mi][ni] = (f32x4)0.f;
    #pragma unroll
    for (int ks = 0; ks < 4; ks++){
      short8 bfr[4];
      #pragma unroll
      for (int ni = 0; ni < 4; ni++){
        int key = ni*16 + l15;
        int cc = (ks*4 + quad) ^ (key & 15);
        bfr[ni] = *(const short8*)&Ks[key*128 + cc*8];
      }
      #pragma unroll
      for (int mi = 0; mi < 2; mi++)
        #pragma unroll
        for (int ni = 0; ni < 4; ni++)
          sa[mi][ni] = mfma16(qf[mi][ks], bfr[ni], sa[mi][ni]);
    }

    // online softmax (rows are wave-local; reduce across the 16-lane col group)
    #pragma unroll
    for (int mi = 0; mi < 2; mi++){
      float rmax[4], rsum[4], al[4];
      #pragma unroll
      for (int r = 0; r < 4; r++)
        rmax[r] = fmaxf(fmaxf(sa[mi][0][r], sa[mi][1][r]), fmaxf(sa[mi][2][r], sa[mi][3][r]));
      #pragma unroll
      for (int off = 1; off <= 8; off <<= 1)
        #pragma unroll
        for (int r = 0; r < 4; r++)
          rmax[r] = fmaxf(rmax[r], __shfl_xor(rmax[r], off));
      #pragma unroll
      for (int r = 0; r < 4; r++){
        float Mn = fmaxf(Mx[mi][r], rmax[r]);
        al[r] = exp2f((Mx[mi][r] - Mn) * LOG2E);
        Mx[mi][r] = Mn;
        rsum[r] = 0.f;
      }
      #pragma unroll
      for (int ni = 0; ni < 4; ni++){
        int colb = ni*16 + l15;
        #pragma unroll
        for (int r = 0; r < 4; r++){
          float pv = exp2f((sa[mi][ni][r] - Mx[mi][r]) * LOG2E);
          rsum[r] += pv;
          int row = w*32 + mi*16 + quad*4 + r;
          int cc = (colb >> 3) ^ (row & 7);
          QsP[row*64 + cc*8 + (colb & 7)] = (short)f2bf(pv);
        }
      }
      #pragma unroll
      for (int off = 1; off <= 8; off <<= 1)
        #pragma unroll
        for (int r = 0; r < 4; r++)
          rsum[r] += __shfl_xor(rsum[r], off);
      #pragma unroll
      for (int r = 0; r < 4; r++) Ln[mi][r] = Ln[mi][r]*al[r] + rsum[r];
      #pragma unroll
      for (int ni = 0; ni < 8; ni++)
        #pragma unroll
        for (int r = 0; r < 4; r++) oacc[mi][ni][r] *= al[r];
    }

    // O += P V  (P from LDS in A-layout, V^T in B-layout)
    #pragma unroll
    for (int ks = 0; ks < 2; ks++){
      short8 pa[2];
      #pragma unroll
      for (int mi = 0; mi < 2; mi++){
        int row = w*32 + mi*16 + l15;
        int cc = (ks*4 + quad) ^ (row & 7);
        pa[mi] = *(const short8*)&QsP[row*64 + cc*8];
      }
      #pragma unroll
      for (int ni = 0; ni < 8; ni++){
        int d = ni*16 + l15;
        int cc = (ks*4 + quad) ^ (d & 7);
        short8 vb = *(const short8*)&Vts[d*64 + cc*8];
        #pragma unroll
        for (int mi = 0; mi < 2; mi++)
          oacc[mi][ni] = mfma16(pa[mi], vb, oacc[mi][ni]);
      }
    }
    __syncthreads();
  }

  // epilogue: divide by l, write fp32 out
  #pragma unroll
  for (int mi = 0; mi < 2; mi++){
    float inv[4];
    #pragma unroll
    for (int r = 0; r < 4; r++) inv[r] = 1.0f / Ln[mi][r];
    #pragma unroll
    for (int ni = 0; ni < 8; ni++)
      #pragma unroll
      for (int r = 0; r < 4; r++){
        int row = w*32 + mi*16 + quad*4 + r;
        int m = b*512 + qt*128 + row;
        out[(size_t)m*4096 + h*128 + ni*16 + l15] = oacc[mi][ni][r] * inv[r];
      }
  }
}

extern "C" void kernel_launch(void* const* d_in, const int* in_sizes, int n_in,
                              void* d_out, int out_size, void* d_ws, size_t ws_size,
                              hipStream_t stream){
  const float* x    = (const float*)d_in[0];
  const int*   spp  = (const int*)d_in[1];
  const float* fcos = (const float*)d_in[2];
  const float* fsin = (const float*)d_in[3];
  const float* wq   = (const float*)d_in[4];
  const float* bq   = (const float*)d_in[5];
  const float* wk   = (const float*)d_in[6];
  const float* bk   = (const float*)d_in[7];
  const float* wv   = (const float*)d_in[8];
  const float* bv   = (const float*)d_in[9];
  float* ck = (float*)d_in[10];
  float* cv = (float*)d_in[11];
  float* out = (float*)d_out;

  unsigned short* xb = (unsigned short*)d_ws;
  unsigned short* Qb = xb + (size_t)2048*4096;
  unsigned short* wb = Qb + (size_t)2048*4096;
  const size_t need_big = (size_t)2*2048*4096*2 + (size_t)3*4096*4096*2; // 128 MiB
  bool big = ws_size >= need_big;

  k_cvt<<<2048, 256, 0, stream>>>(x, xb, 2048*4096/4);
  if (big){
    k_cvt<<<4096, 256, 0, stream>>>(wq, wb,                       4096*4096/4);
    k_cvt<<<4096, 256, 0, stream>>>(wk, wb + (size_t)4096*4096,   4096*4096/4);
    k_cvt<<<4096, 256, 0, stream>>>(wv, wb + (size_t)2*4096*4096, 4096*4096/4);
    k_gemm<1><<<dim3(512,1,3), 256, 0, stream>>>(xb, wb, wq, wk, wv, bq, bk, bv,
                                                 fcos, fsin, spp, Qb, ck, cv);
  } else {
    k_gemm<0><<<dim3(512,1,3), 256, 0, stream>>>(xb, wb, wq, wk, wv, bq, bk, bv,
                                                 fcos, fsin, spp, Qb, ck, cv);
  }
  k_attn<<<512, 256, 0, stream>>>(Qb, ck, cv, spp, out);
}